// Round 1
// baseline (182.303 us; speedup 1.0000x reference)
//
#include <hip/hip_runtime.h>
#include <math.h>

// Problem constants (from reference setup_inputs)
constexpr int B  = 2;
constexpr int Lq = 4096;
constexpr int Lk = 4096;
constexpr int H  = 8;
constexpr int C  = 64;   // == wavefront size
constexpr int K  = 32;
constexpr float INV_SCALE = 1.0f / 8.0f;

// One wave (64 lanes) per query row (b, l, h). Lane = channel c.
// Block = 4 waves = 4 consecutive rows of the same (b,h) group.
// Grid 16384 blocks; group = bid & 15 keeps each (b,h) on one XCD
// (hw round-robins blockIdx % 8), so its 2 MB K+V set stays in that XCD's L2.
__global__ __launch_bounds__(256) void topk_attn_kernel(
    const float* __restrict__ query,
    const float* __restrict__ key,
    const float* __restrict__ value,
    const int*   __restrict__ pos,
    float*       __restrict__ out)
{
    const int bid   = blockIdx.x;          // 0..16383
    const int group = bid & 15;            // b*H + h
    const int lchunk = bid >> 4;           // 0..1023
    const int wave  = threadIdx.x >> 6;
    const int lane  = threadIdx.x & 63;

    const int b = group >> 3;
    const int h = group & 7;
    const int l = lchunk * 4 + wave;       // 0..4095

    const size_t row = ((size_t)(b * Lq + l) * H + h);
    const size_t qoff = row * C;

    const float q = query[qoff + lane];
    // lanes 0..31 hold pos[k=lane]; lanes 32..63 duplicate (harmless, keeps shfl simple)
    const int p = pos[row * K + (lane & 31)];

    const float* kbase = key   + (size_t)b * Lk * H * C + (size_t)h * C;
    const float* vbase = value + (size_t)b * Lk * H * C + (size_t)h * C;

    // ---- scores: lane k (k<32) ends up holding score_k ----
    float score = 0.0f;
    #pragma unroll
    for (int k = 0; k < K; ++k) {
        const int pk = __shfl(p, k);
        const float kv = kbase[(size_t)pk * (H * C) + lane];
        float s = q * kv;
        #pragma unroll
        for (int m = 32; m >= 1; m >>= 1) s += __shfl_xor(s, m);
        if (lane == k) score = s;
    }
    score *= INV_SCALE;

    // ---- softmax across lanes 0..31 ----
    const float sc = (lane < K) ? score : -INFINITY;
    float mx = sc;
    #pragma unroll
    for (int m = 32; m >= 1; m >>= 1) mx = fmaxf(mx, __shfl_xor(mx, m));
    const float e = (lane < K) ? __expf(sc - mx) : 0.0f;
    float se = e;
    #pragma unroll
    for (int m = 32; m >= 1; m >>= 1) se += __shfl_xor(se, m);
    const float attn = e / se;   // lane k holds attn_k (k<32)

    // ---- out[c] = sum_k attn_k * v_k[c] ----
    float acc = 0.0f;
    #pragma unroll
    for (int k = 0; k < K; ++k) {
        const int pk = __shfl(p, k);
        const float a = __shfl(attn, k);
        const float vv = vbase[(size_t)pk * (H * C) + lane];
        acc = fmaf(a, vv, acc);
    }

    out[qoff + lane] = acc;
}

extern "C" void kernel_launch(void* const* d_in, const int* in_sizes, int n_in,
                              void* d_out, int out_size, void* d_ws, size_t ws_size,
                              hipStream_t stream) {
    const float* query = (const float*)d_in[0];
    const float* key   = (const float*)d_in[1];
    const float* value = (const float*)d_in[2];
    const int*   pos   = (const int*)d_in[3];
    float* out = (float*)d_out;

    const int total_rows = B * Lq * H;          // 65536
    const int blocks = total_rows / 4;          // 16384 (4 waves/block)
    topk_attn_kernel<<<blocks, 256, 0, stream>>>(query, key, value, pos, out);
}

// Round 2
// 55.907 us; speedup vs baseline: 3.2608x; 3.2608x over previous
//
#include <hip/hip_runtime.h>
#include <math.h>

// Problem constants (from reference setup_inputs)
constexpr int B  = 2;
constexpr int Lq = 4096;
constexpr int Lk = 4096;
constexpr int H  = 8;
constexpr int C  = 64;
constexpr int K  = 32;
constexpr float INV_SCALE = 0.125f;

// One wave per query row. Wave split into 4 groups of 16 lanes:
//   g  = lane>>4  : key sub-group — group g handles keys {4i+g, i=0..7}
//   c4 = lane&15  : float4 channel slot — channels [4*c4, 4*c4+4)
// K/V rows are 256 B = 16 lanes x float4 -> one dwordx4 load per 4 keys.
// Score reduce: 4-step butterfly over 16 lanes (masks 8,4,2,1).
// attn_i stays lane-local for PV (no shuffles); PV partials combined
// across the 4 groups with masks 16,32.
// XCD pinning: group = bid&15 => all blocks of one (b,h) land on XCD
// (group%8); its 2 MB K+V set stays in that XCD's 4 MB L2.
__global__ __launch_bounds__(256) void topk_attn_kernel(
    const float* __restrict__ query,
    const float* __restrict__ key,
    const float* __restrict__ value,
    const int*   __restrict__ pos,
    float*       __restrict__ out)
{
    const int bid    = blockIdx.x;          // 0..16383
    const int group  = bid & 15;            // b*H + h
    const int lchunk = bid >> 4;            // 0..1023
    const int wave   = threadIdx.x >> 6;
    const int lane   = threadIdx.x & 63;
    const int g      = lane >> 4;           // 0..3
    const int c4     = lane & 15;           // 0..15

    const int b = group >> 3;
    const int h = group & 7;
    const int l = lchunk * 4 + wave;        // 0..4095

    const size_t row  = ((size_t)(b * Lq + l) * H + h);
    const size_t qoff = row * (size_t)C;

    float4 q4 = *(const float4*)(query + qoff + 4 * c4);
    q4.x *= INV_SCALE; q4.y *= INV_SCALE; q4.z *= INV_SCALE; q4.w *= INV_SCALE;

    // lanes 0..31 hold pos[k=lane]; 32..63 duplicate
    const int p = pos[row * K + (lane & 31)];

    const float* kbase = key   + (size_t)b * Lk * H * C + (size_t)h * C;
    const float* vbase = value + (size_t)b * Lk * H * C + (size_t)h * C;

    // gather offsets, known up-front -> all loads can be in flight early
    int off[8];
    #pragma unroll
    for (int i = 0; i < 8; ++i) {
        const int pk = __shfl(p, 4 * i + g);
        off[i] = pk * (H * C) + 4 * c4;
    }

    // ---- scores: s[i] = score of key (4i+g), replicated across the group ----
    float s[8];
    #pragma unroll
    for (int i = 0; i < 8; ++i) {
        const float4 kv = *(const float4*)(kbase + off[i]);
        float t = q4.x * kv.x;
        t = fmaf(q4.y, kv.y, t);
        t = fmaf(q4.z, kv.z, t);
        t = fmaf(q4.w, kv.w, t);
        #pragma unroll
        for (int m = 8; m >= 1; m >>= 1) t += __shfl_xor(t, m);
        s[i] = t;
    }

    // ---- softmax over all 32 keys ----
    float mx = s[0];
    #pragma unroll
    for (int i = 1; i < 8; ++i) mx = fmaxf(mx, s[i]);
    mx = fmaxf(mx, __shfl_xor(mx, 16));
    mx = fmaxf(mx, __shfl_xor(mx, 32));

    float se = 0.0f;
    #pragma unroll
    for (int i = 0; i < 8; ++i) { s[i] = __expf(s[i] - mx); se += s[i]; }
    se += __shfl_xor(se, 16);
    se += __shfl_xor(se, 32);
    const float inv = 1.0f / se;

    // ---- PV: acc4(channels 4*c4) partial over this group's 8 keys ----
    float4 acc = make_float4(0.f, 0.f, 0.f, 0.f);
    #pragma unroll
    for (int i = 0; i < 8; ++i) {
        const float a = s[i] * inv;
        const float4 v4 = *(const float4*)(vbase + off[i]);
        acc.x = fmaf(a, v4.x, acc.x);
        acc.y = fmaf(a, v4.y, acc.y);
        acc.z = fmaf(a, v4.z, acc.z);
        acc.w = fmaf(a, v4.w, acc.w);
    }
    // combine the 4 key-groups
    #pragma unroll
    for (int m = 16; m <= 32; m <<= 1) {
        acc.x += __shfl_xor(acc.x, m);
        acc.y += __shfl_xor(acc.y, m);
        acc.z += __shfl_xor(acc.z, m);
        acc.w += __shfl_xor(acc.w, m);
    }

    if (g == 0) *(float4*)(out + qoff + 4 * c4) = acc;
}

extern "C" void kernel_launch(void* const* d_in, const int* in_sizes, int n_in,
                              void* d_out, int out_size, void* d_ws, size_t ws_size,
                              hipStream_t stream) {
    const float* query = (const float*)d_in[0];
    const float* key   = (const float*)d_in[1];
    const float* value = (const float*)d_in[2];
    const int*   pos   = (const int*)d_in[3];
    float* out = (float*)d_out;

    const int total_rows = B * Lq * H;      // 65536
    const int blocks = total_rows / 4;      // 16384 (4 waves/block)
    topk_attn_kernel<<<blocks, 256, 0, stream>>>(query, key, value, pos, out);
}